// Round 4
// baseline (277.972 us; speedup 1.0000x reference)
//
#include <hip/hip_runtime.h>
#include <hip/hip_fp16.h>

#define B 32
#define R 2048
#define C 32
#define O 32
#define IN 16

typedef _Float16 hf2 __attribute__((ext_vector_type(2)));

// votes_h layout: per (b,c) slice of 65536 halfs; u32 word index rp*32+o holds
// half2(v[2rp][o], v[2rp+1][o]).

// ---------------------------------------------------------------------------
// K1: block = (32-row chunk, c-pair), 512 threads:
//   c = blockIdx.y*2 + (t>>8); rp_l = (t>>4)&15; op = t&15  (o = 2op, 2op+1)
// Thread computes rows (r, r+1) x o-pair = 4 dots per bb via v_dot2_f32_f16.
// Vote rows live in 32 packed-half2 regs (converted once). x staged fp16 LDS.
//
// __launch_bounds__(512, 8): 8 waves/EU -> 64-VGPR budget (kernel uses 36,
// fits) -> 4 blocks/CU (LDS 4x32=128 KB <= 160 KB). Round-3 counters at
// (512,4) showed the latency signature: occupancy 49%, VALUBusy 18%,
// HBM 28%, dur 96 us vs the ~34 us traffic floor — prologue load bursts
// of only 2 resident blocks don't overlap. Doubling residency is the fix.
// ---------------------------------------------------------------------------
__global__ __launch_bounds__(512, 8) void votes_kernel(
    const float* __restrict__ x,     // [B][R][IN] fp32
    const float* __restrict__ vote,  // [R][C][O][IN] fp32
    __half* __restrict__ votes_h)
{
  const int t = threadIdx.x;
  const int c = blockIdx.y * 2 + (t >> 8);
  const int tt = t & 255;
  const int rp_l = tt >> 4;                  // 0..15
  const int op = tt & 15;                    // o-pair
  const int r0 = blockIdx.x * 32;
  const int r = r0 + 2 * rp_l;
  const int rpg = blockIdx.x * 16 + rp_l;    // global row-pair

  __shared__ unsigned int x_lds[32 * 32 * 8];  // [bb][rl][8 words], 32 KB

  // ---- stage x fp32 -> fp16 (4096 float4, 8 per thread, coalesced) ----
#pragma unroll
  for (int k = 0; k < 8; ++k) {
    int j = t + k * 512;
    int bb = j >> 7;
    int rr = (j >> 2) & 31;
    int ic = j & 3;
    float4 v = *reinterpret_cast<const float4*>(
        x + ((size_t)bb * R + r0 + rr) * IN + ic * 4);
    __half2 h01 = __float22half2_rn(make_float2(v.x, v.y));
    __half2 h23 = __float22half2_rn(make_float2(v.z, v.w));
    int w = (bb * 32 + rr) * 8 + 2 * ic;
    x_lds[w] = __builtin_bit_cast(unsigned int, h01);
    x_lds[w + 1] = __builtin_bit_cast(unsigned int, h23);
  }

  // ---- load + convert 4 vote rows (rows r,r+1 x o=2op,2op+1) ----
  unsigned int wh[4][8];
#pragma unroll
  for (int p = 0; p < 2; ++p) {
#pragma unroll
    for (int q = 0; q < 2; ++q) {
      const float4* vp = reinterpret_cast<const float4*>(
          vote + (((size_t)(r + p) * C + c) * O + 2 * op + q) * IN);
#pragma unroll
      for (int k = 0; k < 4; ++k) {
        float4 f = vp[k];
        __half2 a = __float22half2_rn(make_float2(f.x, f.y));
        __half2 d = __float22half2_rn(make_float2(f.z, f.w));
        wh[p * 2 + q][2 * k] = __builtin_bit_cast(unsigned int, a);
        wh[p * 2 + q][2 * k + 1] = __builtin_bit_cast(unsigned int, d);
      }
    }
  }
  __syncthreads();

  __half* ob = votes_h + (size_t)c * 65536 + (size_t)rpg * 64 + op * 4;

#pragma unroll 2
  for (int bb = 0; bb < 32; ++bb) {
    const uint4* xr = reinterpret_cast<const uint4*>(
        &x_lds[(bb * 32 + 2 * rp_l) * 8]);
    uint4 xa = xr[0], xb = xr[1];  // row r   (8 half2)
    uint4 xc = xr[2], xd = xr[3];  // row r+1 (8 half2)
    unsigned int x0[8] = {xa.x, xa.y, xa.z, xa.w, xb.x, xb.y, xb.z, xb.w};
    unsigned int x1[8] = {xc.x, xc.y, xc.z, xc.w, xd.x, xd.y, xd.z, xd.w};
    float a00 = 0.f, a01 = 0.f, a10 = 0.f, a11 = 0.f;
#pragma unroll
    for (int k = 0; k < 8; ++k) {
      hf2 xv0 = __builtin_bit_cast(hf2, x0[k]);
      hf2 xv1 = __builtin_bit_cast(hf2, x1[k]);
      a00 = __builtin_amdgcn_fdot2(__builtin_bit_cast(hf2, wh[0][k]), xv0, a00, false);
      a01 = __builtin_amdgcn_fdot2(__builtin_bit_cast(hf2, wh[1][k]), xv0, a01, false);
      a10 = __builtin_amdgcn_fdot2(__builtin_bit_cast(hf2, wh[2][k]), xv1, a10, false);
      a11 = __builtin_amdgcn_fdot2(__builtin_bit_cast(hf2, wh[3][k]), xv1, a11, false);
    }
    __half2 w0 = __float22half2_rn(make_float2(a00, a10));
    __half2 w1 = __float22half2_rn(make_float2(a01, a11));
    uint2 pk;
    pk.x = __builtin_bit_cast(unsigned int, w0);
    pk.y = __builtin_bit_cast(unsigned int, w1);
    *reinterpret_cast<uint2*>(ob + (size_t)bb * C * 65536) = pk;
  }
}

// ---------------------------------------------------------------------------
// K2: register-resident routing. One block per (b,c), 1024 threads.
// Thread t = (rb = t>>3, q = t&7) owns row-pairs rp = rb + 128k (k=0..7) at
// outputs o = 4q..4q+3, loaded FULLY COALESCED: v[k] = src[t + k*1024].
//
// __launch_bounds__(1024, 4): 4 waves/EU -> 128-VGPR budget. Rounds 1-2
// used (1024, 8) -> 32-VGPR budget -> full scratch spill (400 MB refetch +
// 278 MB scratch writes, 182 us). Round 3 with (1024,4): fixed (~55 us,
// out of top-5). DO NOT raise the min-waves arg here.
//
// Agreement reduce over o: 3-stage butterfly reduce-scatter in the 8-lane
// o-quad group; lane q ends owning rp = rb+128q, the slot it publishes
// exp(a) to. e2s padded (slot = rp + rp/128, stride 129) -> conflict-free.
// ---------------------------------------------------------------------------
#define PIN4(u) asm volatile("" : "+v"(u.x), "+v"(u.y), "+v"(u.z), "+v"(u.w))

__device__ __forceinline__ float rscatter8(const float u[8], int q) {
  // Sum u[j] over the 8-lane group (lanes differing in bits 0..2);
  // lane q receives the group total of u[q].
  const bool h4 = (q & 4) != 0;
  const bool h2 = (q & 2) != 0;
  const bool h1 = (q & 1) != 0;
  float ka = h4 ? u[4] : u[0], sa = h4 ? u[0] : u[4];
  float kb = h4 ? u[5] : u[1], sb = h4 ? u[1] : u[5];
  float kc = h4 ? u[6] : u[2], sc = h4 ? u[2] : u[6];
  float kd = h4 ? u[7] : u[3], sd = h4 ? u[3] : u[7];
  ka += __shfl_xor(sa, 4);
  kb += __shfl_xor(sb, 4);
  kc += __shfl_xor(sc, 4);
  kd += __shfl_xor(sd, 4);
  float pa = h2 ? kc : ka, qa = h2 ? ka : kc;
  float pb = h2 ? kd : kb, qb = h2 ? kb : kd;
  pa += __shfl_xor(qa, 2);
  pb += __shfl_xor(qb, 2);
  float ra = h1 ? pb : pa, rs = h1 ? pa : pb;
  ra += __shfl_xor(rs, 1);
  return ra;
}

__global__ __launch_bounds__(1024, 4) void routing_kernel(
    const __half* __restrict__ votes_h,
    float* __restrict__ out)  // [B][C][O]
{
  const int b = blockIdx.x >> 5;
  const int c = blockIdx.x & 31;
  const int t = threadIdx.x;
  const int lane = t & 63;
  const int wave = t >> 6;   // 0..15
  const int q = t & 7;       // o-quad (o = 4q..4q+3)
  const int rb = t >> 3;     // 0..127; owned row-pairs rp = rb + 128k

  __shared__ float2 e2s[1032];     // padded: slot = rp + (rp>>7)
  __shared__ float4 red4[16][8];   // per-wave S partials, 2 KB
  __shared__ float vdf[32];
  __shared__ float scal_z[16];

  // ---- votes slice straight into registers, fully coalesced ----
  const uint4* src = reinterpret_cast<const uint4*>(
      votes_h + ((size_t)b * C + c) * 65536);
  uint4 v[8];
#pragma unroll
  for (int k = 0; k < 8; ++k) v[k] = src[t + k * 1024];
#pragma unroll
  for (int k = 0; k < 8; ++k) PIN4(v[k]);

  float a0 = 0.f, a1 = 0.f;  // agreement for owned row-pair rb + 128q
  const hf2 ones = {(_Float16)1.0f, (_Float16)1.0f};

#pragma unroll
  for (int iter = 0; iter < 3; ++iter) {
    if (iter > 0) {
      // e-phase: exp + Z partial + publish e2 for the S-pass
      float e0 = __expf(a0), e1 = __expf(a1);
      float z = e0 + e1;
#pragma unroll
      for (int mask = 32; mask; mask >>= 1) z += __shfl_xor(z, mask);
      if (lane == 0) scal_z[wave] = z;
      e2s[rb + 129 * q] = make_float2(e0, e1);
      __syncthreads();
    }

    // ---- S-pass: thread sums its 8 row-pairs at its 4 o's ----
    float s0 = 0.f, s1 = 0.f, s2 = 0.f, s3 = 0.f;
    if (iter == 0) {
#pragma unroll
      for (int k = 0; k < 8; ++k) {
        s0 = __builtin_amdgcn_fdot2(__builtin_bit_cast(hf2, v[k].x), ones, s0, false);
        s1 = __builtin_amdgcn_fdot2(__builtin_bit_cast(hf2, v[k].y), ones, s1, false);
        s2 = __builtin_amdgcn_fdot2(__builtin_bit_cast(hf2, v[k].z), ones, s2, false);
        s3 = __builtin_amdgcn_fdot2(__builtin_bit_cast(hf2, v[k].w), ones, s3, false);
      }
    } else {
#pragma unroll
      for (int k = 0; k < 8; ++k) {
        float2 e = e2s[rb + 129 * k];  // conflict-free; 8-lane broadcast over q
        __half2 h0 = __builtin_bit_cast(__half2, v[k].x);
        __half2 h1 = __builtin_bit_cast(__half2, v[k].y);
        __half2 h2 = __builtin_bit_cast(__half2, v[k].z);
        __half2 h3 = __builtin_bit_cast(__half2, v[k].w);
        s0 += e.x * __low2float(h0) + e.y * __high2float(h0);
        s1 += e.x * __low2float(h1) + e.y * __high2float(h1);
        s2 += e.x * __low2float(h2) + e.y * __high2float(h2);
        s3 += e.x * __low2float(h3) + e.y * __high2float(h3);
      }
    }
    // reduce over the wave's 8 rb subgroups (lanes sharing q)
    s0 += __shfl_xor(s0, 8);  s1 += __shfl_xor(s1, 8);
    s2 += __shfl_xor(s2, 8);  s3 += __shfl_xor(s3, 8);
    s0 += __shfl_xor(s0, 16); s1 += __shfl_xor(s1, 16);
    s2 += __shfl_xor(s2, 16); s3 += __shfl_xor(s3, 16);
    s0 += __shfl_xor(s0, 32); s1 += __shfl_xor(s1, 32);
    s2 += __shfl_xor(s2, 32); s3 += __shfl_xor(s3, 32);
    if (lane < 8) red4[wave][lane] = make_float4(s0, s1, s2, s3);
    __syncthreads();

    // ---- wave 0: finish S, squash, publish verdict ----
    if (t < 32) {
      const float* redf = reinterpret_cast<const float*>(red4);
      float S = 0.f;
#pragma unroll
      for (int w = 0; w < 16; ++w) S += redf[w * 32 + t];
      float Zinv;
      if (iter == 0) {
        Zinv = 1.0f / 2048.0f;
      } else {
        float Z = 0.f;
#pragma unroll
        for (int w = 0; w < 16; ++w) Z += scal_z[w];
        Zinv = 1.0f / Z;
      }
      float summary = S * Zinv;
      float sq = summary * summary;
#pragma unroll
      for (int mask = 16; mask; mask >>= 1) sq += __shfl_xor(sq, mask);
      float scale = sq / ((1.0f + sq) * sqrtf(sq + 1e-8f));
      float vd = summary * scale;
      if (iter < 2) vdf[t] = vd;
      else out[((size_t)b * C + c) * O + t] = vd;
    }

    // ---- agreement update (skipped on last iter) ----
    if (iter < 2) {
      __syncthreads();
      float4 vd4 = *reinterpret_cast<const float4*>(&vdf[4 * q]);
      float u[8];
      // even rows
#pragma unroll
      for (int k = 0; k < 8; ++k) {
        __half2 h0 = __builtin_bit_cast(__half2, v[k].x);
        __half2 h1 = __builtin_bit_cast(__half2, v[k].y);
        __half2 h2 = __builtin_bit_cast(__half2, v[k].z);
        __half2 h3 = __builtin_bit_cast(__half2, v[k].w);
        u[k] = __low2float(h0) * vd4.x + __low2float(h1) * vd4.y +
               __low2float(h2) * vd4.z + __low2float(h3) * vd4.w;
      }
      a0 += rscatter8(u, q);
      // odd rows
#pragma unroll
      for (int k = 0; k < 8; ++k) {
        __half2 h0 = __builtin_bit_cast(__half2, v[k].x);
        __half2 h1 = __builtin_bit_cast(__half2, v[k].y);
        __half2 h2 = __builtin_bit_cast(__half2, v[k].z);
        __half2 h3 = __builtin_bit_cast(__half2, v[k].w);
        u[k] = __high2float(h0) * vd4.x + __high2float(h1) * vd4.y +
               __high2float(h2) * vd4.z + __high2float(h3) * vd4.w;
      }
      a1 += rscatter8(u, q);
    }
  }
}

extern "C" void kernel_launch(void* const* d_in, const int* in_sizes, int n_in,
                              void* d_out, int out_size, void* d_ws, size_t ws_size,
                              hipStream_t stream) {
  const float* x = (const float*)d_in[0];     // [32][2048][16]
  const float* vote = (const float*)d_in[1];  // [2048][32][32][16]
  float* out = (float*)d_out;                 // [32][32][32]
  __half* votes_h = (__half*)d_ws;            // 134 MB interleaved

  votes_kernel<<<dim3(R / 32, C / 2), 512, 0, stream>>>(x, vote, votes_h);
  routing_kernel<<<dim3(B * C), 1024, 0, stream>>>(votes_h, out);
}

// Round 5
// 273.761 us; speedup vs baseline: 1.0154x; 1.0154x over previous
//
#include <hip/hip_runtime.h>
#include <hip/hip_fp16.h>

#define B 32
#define R 2048
#define C 32
#define O 32
#define IN 16

typedef _Float16 hf2 __attribute__((ext_vector_type(2)));

// votes_h layout: per (b,c) slice of 65536 halfs; u32 word index rp*32+o holds
// half2(v[2rp][o], v[2rp+1][o]).

// ---------------------------------------------------------------------------
// K1: block = (32-row chunk, c-pair), 512 threads.
//   cc = t>>8 (c half), rp_l = (t>>4)&15, op = t&15 (o = 2op, 2op+1)
//
// Round-4 lesson: at (512,8) occupancy rose 49->57% with ZERO dur change ->
// occupancy is NOT the binding resource. VALU 18%, HBM 28%, LDS-conflict 0
// -> the saturated pipe is the vector-memory transaction path: direct vote
// fragment loads make 16 lanes read 16 B at 128-B stride = 64 cache lines
// per instruction (8x amplification), ~537M line-transactions per kernel.
//
// Fix: ALL global loads wave-contiguous. Vote tile (32 rows x 2 c = 128 KB
// fp32) is staged coalesced -> fp16 -> 64 KB LDS; each thread extracts its
// 4 fragments once (8 x ds_read_b128, one-time); then the x buffer REUSES
// the same LDS (vote buffer dead after extraction). LDS = 64 KB -> 2
// blocks/CU at (512,4) (128-VGPR budget, wh[32]+temps fit with slack).
// ---------------------------------------------------------------------------
__global__ __launch_bounds__(512, 4) void votes_kernel(
    const float* __restrict__ x,     // [B][R][IN] fp32
    const float* __restrict__ vote,  // [R][C][O][IN] fp32
    __half* __restrict__ votes_h)
{
  const int t = threadIdx.x;
  const int cc = t >> 8;                     // c half (0/1)
  const int c0 = blockIdx.y * 2;
  const int c = c0 + cc;
  const int tt = t & 255;
  const int rp_l = tt >> 4;                  // 0..15
  const int op = tt & 15;                    // o-pair
  const int r0 = blockIdx.x * 32;
  const int rpg = blockIdx.x * 16 + rp_l;    // global row-pair

  // 64 KB, two lives: phase 1 = vote tile fp16 (64 slices x 256 words),
  // phase 3+ = x tile fp16 (words 0..8191).
  __shared__ unsigned int lds[16384];

  // ---- phase 1: stage vote tile, fully coalesced (8192 float4, 16/thread).
  // slice = row*2 + c2 (0..63); each slice = one (row,c) [O][IN] run of
  // 2048 B contiguous in global = 128 float4. Wave = 1 KB contiguous.
#pragma unroll
  for (int k = 0; k < 16; ++k) {
    int j = t + k * 512;
    int slice = j >> 7;          // 0..63
    int pos = j & 127;           // float4 within slice
    int row = slice >> 1;
    int c2 = slice & 1;
    float4 f = reinterpret_cast<const float4*>(
        vote + ((size_t)(r0 + row) * C + c0 + c2) * O * IN)[pos];
    __half2 a = __float22half2_rn(make_float2(f.x, f.y));
    __half2 d = __float22half2_rn(make_float2(f.z, f.w));
    uint2 w;
    w.x = __builtin_bit_cast(unsigned int, a);
    w.y = __builtin_bit_cast(unsigned int, d);
    *reinterpret_cast<uint2*>(&lds[slice * 256 + pos * 2]) = w;
  }
  __syncthreads();

  // ---- phase 2: extract 4 vote fragments (rows 2rp_l, 2rp_l+1 x o-pair)
  // from LDS. One-time: 8 x ds_read_b128 per thread.
  unsigned int wh[4][8];
#pragma unroll
  for (int p = 0; p < 2; ++p) {
#pragma unroll
    for (int q = 0; q < 2; ++q) {
      const int slice = ((2 * rp_l + p) << 1) | cc;
      const uint4* fp = reinterpret_cast<const uint4*>(
          &lds[slice * 256 + (2 * op + q) * 8]);
      uint4 lo = fp[0], hi = fp[1];
      wh[p * 2 + q][0] = lo.x; wh[p * 2 + q][1] = lo.y;
      wh[p * 2 + q][2] = lo.z; wh[p * 2 + q][3] = lo.w;
      wh[p * 2 + q][4] = hi.x; wh[p * 2 + q][5] = hi.y;
      wh[p * 2 + q][6] = hi.z; wh[p * 2 + q][7] = hi.w;
    }
  }
  __syncthreads();  // vote buffer fully consumed; safe to overwrite

  // ---- phase 3: stage x fp32 -> fp16 into the same LDS (words 0..8191) ----
#pragma unroll
  for (int k = 0; k < 8; ++k) {
    int j = t + k * 512;
    int bb = j >> 7;
    int rr = (j >> 2) & 31;
    int ic = j & 3;
    float4 v = *reinterpret_cast<const float4*>(
        x + ((size_t)bb * R + r0 + rr) * IN + ic * 4);
    __half2 h01 = __float22half2_rn(make_float2(v.x, v.y));
    __half2 h23 = __float22half2_rn(make_float2(v.z, v.w));
    int w = (bb * 32 + rr) * 8 + 2 * ic;
    lds[w] = __builtin_bit_cast(unsigned int, h01);
    lds[w + 1] = __builtin_bit_cast(unsigned int, h23);
  }
  __syncthreads();

  __half* ob = votes_h + (size_t)c * 65536 + (size_t)rpg * 64 + op * 4;

#pragma unroll 2
  for (int bb = 0; bb < 32; ++bb) {
    const uint4* xr = reinterpret_cast<const uint4*>(
        &lds[(bb * 32 + 2 * rp_l) * 8]);
    uint4 xa = xr[0], xb = xr[1];  // row r   (8 half2)
    uint4 xc = xr[2], xd = xr[3];  // row r+1 (8 half2)
    unsigned int x0[8] = {xa.x, xa.y, xa.z, xa.w, xb.x, xb.y, xb.z, xb.w};
    unsigned int x1[8] = {xc.x, xc.y, xc.z, xc.w, xd.x, xd.y, xd.z, xd.w};
    float a00 = 0.f, a01 = 0.f, a10 = 0.f, a11 = 0.f;
#pragma unroll
    for (int k = 0; k < 8; ++k) {
      hf2 xv0 = __builtin_bit_cast(hf2, x0[k]);
      hf2 xv1 = __builtin_bit_cast(hf2, x1[k]);
      a00 = __builtin_amdgcn_fdot2(__builtin_bit_cast(hf2, wh[0][k]), xv0, a00, false);
      a01 = __builtin_amdgcn_fdot2(__builtin_bit_cast(hf2, wh[1][k]), xv0, a01, false);
      a10 = __builtin_amdgcn_fdot2(__builtin_bit_cast(hf2, wh[2][k]), xv1, a10, false);
      a11 = __builtin_amdgcn_fdot2(__builtin_bit_cast(hf2, wh[3][k]), xv1, a11, false);
    }
    __half2 w0 = __float22half2_rn(make_float2(a00, a10));
    __half2 w1 = __float22half2_rn(make_float2(a01, a11));
    uint2 pk;
    pk.x = __builtin_bit_cast(unsigned int, w0);
    pk.y = __builtin_bit_cast(unsigned int, w1);
    *reinterpret_cast<uint2*>(ob + (size_t)bb * C * 65536) = pk;
  }
}

// ---------------------------------------------------------------------------
// K2: register-resident routing. One block per (b,c), 1024 threads.
// Thread t = (rb = t>>3, q = t&7) owns row-pairs rp = rb + 128k (k=0..7) at
// outputs o = 4q..4q+3, loaded FULLY COALESCED: v[k] = src[t + k*1024].
//
// __launch_bounds__(1024, 4): 4 waves/EU -> 128-VGPR budget. Rounds 1-2
// used (1024, 8) -> 32-VGPR budget -> full scratch spill (400 MB refetch +
// 278 MB scratch writes, 182 us). Round 3 with (1024,4): fixed (~55-85 us,
// out of top-5). DO NOT raise the min-waves arg here.
//
// Agreement reduce over o: 3-stage butterfly reduce-scatter in the 8-lane
// o-quad group; lane q ends owning rp = rb+128q, the slot it publishes
// exp(a) to. e2s padded (slot = rp + rp/128, stride 129) -> conflict-free.
// ---------------------------------------------------------------------------
#define PIN4(u) asm volatile("" : "+v"(u.x), "+v"(u.y), "+v"(u.z), "+v"(u.w))

__device__ __forceinline__ float rscatter8(const float u[8], int q) {
  // Sum u[j] over the 8-lane group (lanes differing in bits 0..2);
  // lane q receives the group total of u[q].
  const bool h4 = (q & 4) != 0;
  const bool h2 = (q & 2) != 0;
  const bool h1 = (q & 1) != 0;
  float ka = h4 ? u[4] : u[0], sa = h4 ? u[0] : u[4];
  float kb = h4 ? u[5] : u[1], sb = h4 ? u[1] : u[5];
  float kc = h4 ? u[6] : u[2], sc = h4 ? u[2] : u[6];
  float kd = h4 ? u[7] : u[3], sd = h4 ? u[3] : u[7];
  ka += __shfl_xor(sa, 4);
  kb += __shfl_xor(sb, 4);
  kc += __shfl_xor(sc, 4);
  kd += __shfl_xor(sd, 4);
  float pa = h2 ? kc : ka, qa = h2 ? ka : kc;
  float pb = h2 ? kd : kb, qb = h2 ? kb : kd;
  pa += __shfl_xor(qa, 2);
  pb += __shfl_xor(qb, 2);
  float ra = h1 ? pb : pa, rs = h1 ? pa : pb;
  ra += __shfl_xor(rs, 1);
  return ra;
}

__global__ __launch_bounds__(1024, 4) void routing_kernel(
    const __half* __restrict__ votes_h,
    float* __restrict__ out)  // [B][C][O]
{
  const int b = blockIdx.x >> 5;
  const int c = blockIdx.x & 31;
  const int t = threadIdx.x;
  const int lane = t & 63;
  const int wave = t >> 6;   // 0..15
  const int q = t & 7;       // o-quad (o = 4q..4q+3)
  const int rb = t >> 3;     // 0..127; owned row-pairs rp = rb + 128k

  __shared__ float2 e2s[1032];     // padded: slot = rp + (rp>>7)
  __shared__ float4 red4[16][8];   // per-wave S partials, 2 KB
  __shared__ float vdf[32];
  __shared__ float scal_z[16];

  // ---- votes slice straight into registers, fully coalesced ----
  const uint4* src = reinterpret_cast<const uint4*>(
      votes_h + ((size_t)b * C + c) * 65536);
  uint4 v[8];
#pragma unroll
  for (int k = 0; k < 8; ++k) v[k] = src[t + k * 1024];
#pragma unroll
  for (int k = 0; k < 8; ++k) PIN4(v[k]);

  float a0 = 0.f, a1 = 0.f;  // agreement for owned row-pair rb + 128q
  const hf2 ones = {(_Float16)1.0f, (_Float16)1.0f};

#pragma unroll
  for (int iter = 0; iter < 3; ++iter) {
    if (iter > 0) {
      // e-phase: exp + Z partial + publish e2 for the S-pass
      float e0 = __expf(a0), e1 = __expf(a1);
      float z = e0 + e1;
#pragma unroll
      for (int mask = 32; mask; mask >>= 1) z += __shfl_xor(z, mask);
      if (lane == 0) scal_z[wave] = z;
      e2s[rb + 129 * q] = make_float2(e0, e1);
      __syncthreads();
    }

    // ---- S-pass: thread sums its 8 row-pairs at its 4 o's ----
    float s0 = 0.f, s1 = 0.f, s2 = 0.f, s3 = 0.f;
    if (iter == 0) {
#pragma unroll
      for (int k = 0; k < 8; ++k) {
        s0 = __builtin_amdgcn_fdot2(__builtin_bit_cast(hf2, v[k].x), ones, s0, false);
        s1 = __builtin_amdgcn_fdot2(__builtin_bit_cast(hf2, v[k].y), ones, s1, false);
        s2 = __builtin_amdgcn_fdot2(__builtin_bit_cast(hf2, v[k].z), ones, s2, false);
        s3 = __builtin_amdgcn_fdot2(__builtin_bit_cast(hf2, v[k].w), ones, s3, false);
      }
    } else {
#pragma unroll
      for (int k = 0; k < 8; ++k) {
        float2 e = e2s[rb + 129 * k];  // conflict-free; 8-lane broadcast over q
        __half2 h0 = __builtin_bit_cast(__half2, v[k].x);
        __half2 h1 = __builtin_bit_cast(__half2, v[k].y);
        __half2 h2 = __builtin_bit_cast(__half2, v[k].z);
        __half2 h3 = __builtin_bit_cast(__half2, v[k].w);
        s0 += e.x * __low2float(h0) + e.y * __high2float(h0);
        s1 += e.x * __low2float(h1) + e.y * __high2float(h1);
        s2 += e.x * __low2float(h2) + e.y * __high2float(h2);
        s3 += e.x * __low2float(h3) + e.y * __high2float(h3);
      }
    }
    // reduce over the wave's 8 rb subgroups (lanes sharing q)
    s0 += __shfl_xor(s0, 8);  s1 += __shfl_xor(s1, 8);
    s2 += __shfl_xor(s2, 8);  s3 += __shfl_xor(s3, 8);
    s0 += __shfl_xor(s0, 16); s1 += __shfl_xor(s1, 16);
    s2 += __shfl_xor(s2, 16); s3 += __shfl_xor(s3, 16);
    s0 += __shfl_xor(s0, 32); s1 += __shfl_xor(s1, 32);
    s2 += __shfl_xor(s2, 32); s3 += __shfl_xor(s3, 32);
    if (lane < 8) red4[wave][lane] = make_float4(s0, s1, s2, s3);
    __syncthreads();

    // ---- wave 0: finish S, squash, publish verdict ----
    if (t < 32) {
      const float* redf = reinterpret_cast<const float*>(red4);
      float S = 0.f;
#pragma unroll
      for (int w = 0; w < 16; ++w) S += redf[w * 32 + t];
      float Zinv;
      if (iter == 0) {
        Zinv = 1.0f / 2048.0f;
      } else {
        float Z = 0.f;
#pragma unroll
        for (int w = 0; w < 16; ++w) Z += scal_z[w];
        Zinv = 1.0f / Z;
      }
      float summary = S * Zinv;
      float sq = summary * summary;
#pragma unroll
      for (int mask = 16; mask; mask >>= 1) sq += __shfl_xor(sq, mask);
      float scale = sq / ((1.0f + sq) * sqrtf(sq + 1e-8f));
      float vd = summary * scale;
      if (iter < 2) vdf[t] = vd;
      else out[((size_t)b * C + c) * O + t] = vd;
    }

    // ---- agreement update (skipped on last iter) ----
    if (iter < 2) {
      __syncthreads();
      float4 vd4 = *reinterpret_cast<const float4*>(&vdf[4 * q]);
      float u[8];
      // even rows
#pragma unroll
      for (int k = 0; k < 8; ++k) {
        __half2 h0 = __builtin_bit_cast(__half2, v[k].x);
        __half2 h1 = __builtin_bit_cast(__half2, v[k].y);
        __half2 h2 = __builtin_bit_cast(__half2, v[k].z);
        __half2 h3 = __builtin_bit_cast(__half2, v[k].w);
        u[k] = __low2float(h0) * vd4.x + __low2float(h1) * vd4.y +
               __low2float(h2) * vd4.z + __low2float(h3) * vd4.w;
      }
      a0 += rscatter8(u, q);
      // odd rows
#pragma unroll
      for (int k = 0; k < 8; ++k) {
        __half2 h0 = __builtin_bit_cast(__half2, v[k].x);
        __half2 h1 = __builtin_bit_cast(__half2, v[k].y);
        __half2 h2 = __builtin_bit_cast(__half2, v[k].z);
        __half2 h3 = __builtin_bit_cast(__half2, v[k].w);
        u[k] = __high2float(h0) * vd4.x + __high2float(h1) * vd4.y +
               __high2float(h2) * vd4.z + __high2float(h3) * vd4.w;
      }
      a1 += rscatter8(u, q);
    }
  }
}

extern "C" void kernel_launch(void* const* d_in, const int* in_sizes, int n_in,
                              void* d_out, int out_size, void* d_ws, size_t ws_size,
                              hipStream_t stream) {
  const float* x = (const float*)d_in[0];     // [32][2048][16]
  const float* vote = (const float*)d_in[1];  // [2048][32][32][16]
  float* out = (float*)d_out;                 // [32][32][32]
  __half* votes_h = (__half*)d_ws;            // 134 MB interleaved

  votes_kernel<<<dim3(R / 32, C / 2), 512, 0, stream>>>(x, vote, votes_h);
  routing_kernel<<<dim3(B * C), 1024, 0, stream>>>(votes_h, out);
}